// Round 9
// baseline (56.667 us; speedup 1.0000x reference)
//
#include <hip/hip_runtime.h>

typedef unsigned long long ull;
#define NT 100
#define MAGIC 0x5EEDF00DCAFEB0B5ull

// Lock-free min-root union-find in LDS. Parent strictly decreases along
// chains -> termination, no cycles. Final root of each component is its
// minimum slot id -> root set is schedule-invariant (deterministic).
__device__ __forceinline__ int find_root(int* P, int x) {
    int p = P[x];
    while (p != x) {
        int gp = P[p];
        P[x] = gp;          // benign racy path-halving (gp is an ancestor, gp < x)
        x = gp;
        p = P[x];
    }
    return x;
}

__device__ __forceinline__ void unite(int* P, int a, int b) {
    a = find_root(P, a);
    b = find_root(P, b);
    while (a != b) {
        if (a < b) { int t = a; a = b; b = t; }   // hook larger under smaller
        int old = atomicCAS(&P[a], a, b);
        if (old == a) return;
        a = find_root(P, old);
        b = find_root(P, b);
    }
}

// ws layout: partials ws[0..6399] (per-wave packed u64), flags ws[6400..12799].
// Partial blocks (bid<1600): one per (b,c,t); wave h owns cols [16h,16h+16).
// Finisher blocks (bid>=1600): one per b; spin on flags, combine, store out[b].
__global__ __launch_bounds__(256)
void betti_fused(const float* __restrict__ prob,   // [8,3,64,64]
                 const int*  __restrict__ gt,      // [8,3,100,2]
                 ull* __restrict__ ws,
                 float* __restrict__ out)          // [8]
{
    __shared__ int P[2048];
    __shared__ int bL[3][64];
    __shared__ int bR[3][64];
    __shared__ int wsum[4];

    const int bid = blockIdx.x;
    const int tid = threadIdx.x;

    if (bid >= 1600) {
        // ---------------- finisher block for b = bid-1600 ----------------
        const int b = bid - 1600;
        int contrib = 0;
        if (tid < 200) {                          // tid = c*100 + t
            const int tile = b * 200 + tid;       // == (b*2+c)*100 + t
            ull s = 0;
            #pragma unroll
            for (int h = 0; h < 4; ++h) {
                while (__hip_atomic_load(&ws[6400 + tile * 4 + h],
                                         __ATOMIC_ACQUIRE,
                                         __HIP_MEMORY_SCOPE_AGENT) != MAGIC) { }
                s += __hip_atomic_load(&ws[tile * 4 + h],
                                       __ATOMIC_RELAXED,
                                       __HIP_MEMORY_SCOPE_AGENT);
            }
            const int px = (int)( s        & 0xFFFF);
            const int eh = (int)((s >> 16) & 0xFFFF);
            const int ev = (int)((s >> 32) & 0xFFFF);
            const int b0 = (int)((s >> 48) & 0xFFFF);
            const int b1 = b0 - (px - (eh + ev));

            const int c = tid / 100;
            const int t = tid - c * 100;
            int d;
            if (c == 0) {
                const int* g0 = gt + (((size_t)b * 3 + 0) * NT + t) * 2;
                const int* g2 = gt + (((size_t)b * 3 + 2) * NT + t) * 2;
                d = b0 - g0[0]; contrib += d < 0 ? -d : d;
                d = b1 - g0[1]; contrib += d < 0 ? -d : d;
                d = b0 - g2[0]; contrib += d < 0 ? -d : d;
                d = b1 - g2[1]; contrib += d < 0 ? -d : d;
            } else {
                const int* g1 = gt + (((size_t)b * 3 + 1) * NT + t) * 2;
                d = b0 - g1[0]; contrib += d < 0 ? -d : d;
                d = b1 - g1[1]; contrib += d < 0 ? -d : d;
            }
        }
        #pragma unroll
        for (int o = 32; o > 0; o >>= 1) contrib += __shfl_down(contrib, o, 64);
        if ((tid & 63) == 0) wsum[tid >> 6] = contrib;
        __syncthreads();
        if (tid == 0)
            out[b] = (float)(wsum[0] + wsum[1] + wsum[2] + wsum[3]);
        return;
    }

    // ---------------- partial block: one (b,c,t) tile ----------------
    const int t  = bid % NT;
    const int cb = bid / NT;

    const float thr = (float)t * (1.0f / 99.0f);
    const float* img = prob + (size_t)((cb >> 1) * 3 + (cb & 1)) * 4096;

    const int h    = tid >> 6;                // wave = column quarter
    const int lane = tid & 63;                // row

    // load row `lane`, cols 16h..16h+15 (4 x float4), build 16-bit mask
    const float4* rp = (const float4*)(img + (lane << 6) + (h << 4));
    unsigned int m = 0;
    #pragma unroll
    for (int q = 0; q < 4; ++q) {
        float4 v = rp[q];
        m |= (unsigned)(v.x > thr) << (4 * q + 0);
        m |= (unsigned)(v.y > thr) << (4 * q + 1);
        m |= (unsigned)(v.z > thr) << (4 * q + 2);
        m |= (unsigned)(v.w > thr) << (4 * q + 3);
    }

    // init my 8 UF slots (only my wave touches them pre-barrier)
    #pragma unroll
    for (int k = 0; k < 8; ++k) {
        int s = ((h * 8 + k) << 6) | lane;
        P[s] = s;
    }

    const unsigned um = m & 0xFFFFu;
    unsigned up        = (unsigned)__shfl_up((int)um, 1, 64);
    unsigned starts    = um & ~(um << 1) & 0xFFFFu;
    unsigned starts_up = (unsigned)__shfl_up((int)starts, 1, 64);
    if (lane == 0) { up = 0u; starts_up = 0u; }

    const int px    = __popc(um);
    int       eh    = __popc(um & (um >> 1));
    const int ev    = __popc(um & up);
    const int nruns = __popc(starts);

    // boundary descriptors (written pre-barrier, read post-barrier)
    if (h < 3)
        bL[h][lane] = ((um >> 15) & 1u) ? (((h * 8 + (nruns - 1)) << 6) | lane) : -1;
    if (h > 0)
        bR[h - 1][lane] = (um & 1u) ? (((h * 8) << 6) | lane) : -1;

    // within-quarter vertical-overlap unions (own slots only: no barrier)
    unsigned ov = um & up;
    unsigned ss = ov & ~(ov << 1) & 0xFFFFu;
    while (ss) {
        int j = __ffs(ss) - 1;
        ss &= ss - 1;
        unsigned le = (2u << j) - 1;
        int kc = __popc(starts    & le) - 1;
        int ku = __popc(starts_up & le) - 1;
        unite(P, ((h * 8 + kc) << 6) | lane, ((h * 8 + ku) << 6) | (lane - 1));
    }

    __syncthreads();   // inits + bL/bR + disjoint within-unions visible

    // boundary unions + crossing horizontal edges (waves 0..2)
    if (h < 3) {
        int l = bL[h][lane], r = bR[h][lane];
        if (l >= 0 && r >= 0) { eh++; unite(P, l, r); }
    }

    __syncthreads();   // forest quiescent -> root set deterministic

    // roots among my 8 slots, minus phantoms (untouched => self-rooted)
    int selfc = 0;
    #pragma unroll
    for (int k = 0; k < 8; ++k) {
        int s = ((h * 8 + k) << 6) | lane;
        selfc += (P[s] == s) ? 1 : 0;
    }
    const int roots = selfc - (8 - nruns);

    // packed {px|eh|ev|roots} (16b fields) wave reduce; per-wave publish.
    // per-wave sums <= 1024 per field -> no inter-field carry.
    ull pk = (ull)px
           | ((ull)eh    << 16)
           | ((ull)ev    << 32)
           | ((ull)roots << 48);
    #pragma unroll
    for (int o = 32; o > 0; o >>= 1)
        pk += __shfl_down(pk, o, 64);

    if (lane == 0) {
        const int idx = bid * 4 + h;
        __hip_atomic_store(&ws[idx], pk,
                           __ATOMIC_RELAXED, __HIP_MEMORY_SCOPE_AGENT);
        __hip_atomic_store(&ws[6400 + idx], MAGIC,
                           __ATOMIC_RELEASE, __HIP_MEMORY_SCOPE_AGENT);
    }
}

extern "C" void kernel_launch(void* const* d_in, const int* in_sizes, int n_in,
                              void* d_out, int out_size, void* d_ws, size_t ws_size,
                              hipStream_t stream) {
    const float* prob = (const float*)d_in[0];   // [8,3,64,64] f32
    const int*   gt   = (const int*)d_in[1];     // [8,3,100,2] i32
    float* out = (float*)d_out;                  // [8] f32
    ull* ws = (ull*)d_ws;                        // 12800 u64 (100 KiB, proven fits)

    const int nblocks = 1600 + 8;    // 1600 tiles + 8 finishers
    betti_fused<<<nblocks, 256, 0, stream>>>(prob, gt, ws, out);
}

// Round 10
// 33.088 us; speedup vs baseline: 1.7126x; 1.7126x over previous
//
#include <hip/hip_runtime.h>

typedef unsigned long long ull;
#define NT 100

// Lock-free min-root union-find in LDS. Parent strictly decreases along
// chains -> termination, no cycles.
__device__ __forceinline__ int find_root(int* P, int x) {
    int p = P[x];
    while (p != x) {
        int gp = P[p];
        P[x] = gp;          // benign racy path-halving (gp is an ancestor, gp < x)
        x = gp;
        p = P[x];
    }
    return x;
}

// Returns 1 iff this call performed the hook (merged two distinct trees).
// Per-BLOCK total of successful hooks == components merged: schedule-
// invariant (= total runs - final component count), so the block-combined
// value is deterministic even though per-lane attribution races.
__device__ __forceinline__ int unite(int* P, int a, int b) {
    a = find_root(P, a);
    b = find_root(P, b);
    while (a != b) {
        if (a < b) { int t = a; a = b; b = t; }   // hook larger under smaller
        int old = atomicCAS(&P[a], a, b);
        if (old == a) return 1;
        a = find_root(P, old);
        b = find_root(P, b);
    }
    return 0;
}

// One 256-thread block per (b, c, t). Wave h owns column quarter
// [16h, 16h+16); lane r of wave h owns row r of that quarter (16-bit mask).
// Run id = ((h*8 + k) << 6) | row,  k < 8.  tid0 atomicAdds |betti-gt| into
// out[b] (integer-valued float adds < 2^24: exact & order-independent).
__global__ __launch_bounds__(256)
void betti_block(const float* __restrict__ prob,   // [8,3,64,64]
                 const int*  __restrict__ gt,      // [8,3,100,2]
                 float* __restrict__ out)          // [8], pre-zeroed
{
    __shared__ int P[2048];
    __shared__ int bL[3][64];                 // run id at col 16h+15, or -1
    __shared__ int bR[3][64];                 // run id at col 16(h+1), or -1
    __shared__ ull wred[4];

    const int bid = blockIdx.x;               // (b*2 + c)*100 + t
    const int t   = bid % NT;
    const int cb  = bid / NT;
    const int c   = cb & 1;
    const int b   = cb >> 1;

    const float thr = (float)t * (1.0f / 99.0f);
    const float* img = prob + (size_t)(b * 3 + c) * 4096;

    const int tid  = threadIdx.x;
    const int h    = tid >> 6;                // wave = column quarter
    const int lane = tid & 63;                // row

    // ---- load row `lane`, cols 16h..16h+15 (4 x float4), build 16-bit mask ----
    const float4* rp = (const float4*)(img + (lane << 6) + (h << 4));
    unsigned int m = 0;
    #pragma unroll
    for (int q = 0; q < 4; ++q) {
        float4 v = rp[q];
        m |= (unsigned)(v.x > thr) << (4 * q + 0);
        m |= (unsigned)(v.y > thr) << (4 * q + 1);
        m |= (unsigned)(v.z > thr) << (4 * q + 2);
        m |= (unsigned)(v.w > thr) << (4 * q + 3);
    }

    // ---- init my 8 UF slots (only my wave touches them pre-barrier) ----
    #pragma unroll
    for (int k = 0; k < 8; ++k) {
        int s = ((h * 8 + k) << 6) | lane;
        P[s] = s;
    }

    const unsigned um = m & 0xFFFFu;
    unsigned up        = (unsigned)__shfl_up((int)um, 1, 64);
    unsigned starts    = um & ~(um << 1) & 0xFFFFu;       // run starts
    unsigned starts_up = (unsigned)__shfl_up((int)starts, 1, 64);
    if (lane == 0) { up = 0u; starts_up = 0u; }

    const int px    = __popc(um);
    int       eh    = __popc(um & (um >> 1));             // horiz edges in quarter
    const int ev    = __popc(um & up);                    // vert edges in quarter
    const int nruns = __popc(starts);

    // ---- boundary descriptors (written pre-barrier, read post-barrier) ----
    if (h < 3)   // run containing col15 is the last-starting run: index nruns-1
        bL[h][lane] = ((um >> 15) & 1u) ? (((h * 8 + (nruns - 1)) << 6) | lane) : -1;
    if (h > 0)   // if col 16h is set, it is a run start: index 0
        bR[h - 1][lane] = (um & 1u) ? (((h * 8) << 6) | lane) : -1;

    // ---- within-quarter vertical-overlap unions (own slots only) ----
    int merges = 0;
    unsigned ov = um & up;
    unsigned ss = ov & ~(ov << 1) & 0xFFFFu;              // segment starts
    while (ss) {
        int j = __ffs(ss) - 1;
        ss &= ss - 1;
        unsigned le = (2u << j) - 1;                      // bits [0..j]
        int kc = __popc(starts    & le) - 1;
        int ku = __popc(starts_up & le) - 1;
        merges += unite(P, ((h * 8 + kc) << 6) | lane, ((h * 8 + ku) << 6) | (lane - 1));
    }

    __syncthreads();   // all inits + bL/bR + (disjoint) within-unions visible

    // ---- boundary unions + crossing horizontal edges (waves 0..2) ----
    if (h < 3) {
        int l = bL[h][lane], r = bR[h][lane];
        if (l >= 0 && r >= 0) { eh++; merges += unite(P, l, r); }
    }

    // ---- packed {px(13)|eh(12)|ev(12)|nruns(12)|merges(12)} wave reduce ----
    // block totals: px<=4096, eh<=4032, ev<=4032, nruns<=2048, merges<2048
    ull pk = (ull)px
           | ((ull)eh     << 13)
           | ((ull)ev     << 25)
           | ((ull)nruns  << 37)
           | ((ull)merges << 49);
    #pragma unroll
    for (int o = 32; o > 0; o >>= 1)
        pk += __shfl_down(pk, o, 64);
    if (lane == 0) wred[h] = pk;
    __syncthreads();

    if (tid == 0) {
        ull s = wred[0] + wred[1] + wred[2] + wred[3];
        const int spx = (int)( s        & 0x1FFF);
        const int seh = (int)((s >> 13) & 0xFFF);
        const int sev = (int)((s >> 25) & 0xFFF);
        const int nr  = (int)((s >> 37) & 0xFFF);
        const int mg  = (int)((s >> 49) & 0xFFF);
        const int b0  = nr - mg;
        const int b1  = b0 - (spx - (seh + sev));

        int contrib = 0, d;
        if (c == 0) {
            const int* g0 = gt + (((size_t)b * 3 + 0) * NT + t) * 2;
            const int* g2 = gt + (((size_t)b * 3 + 2) * NT + t) * 2;
            d = b0 - g0[0]; contrib += d < 0 ? -d : d;
            d = b1 - g0[1]; contrib += d < 0 ? -d : d;
            d = b0 - g2[0]; contrib += d < 0 ? -d : d;
            d = b1 - g2[1]; contrib += d < 0 ? -d : d;
        } else {
            const int* g1 = gt + (((size_t)b * 3 + 1) * NT + t) * 2;
            d = b0 - g1[0]; contrib += d < 0 ? -d : d;
            d = b1 - g1[1]; contrib += d < 0 ? -d : d;
        }
        atomicAdd(&out[b], (float)contrib);   // exact: integer-valued floats
    }
}

extern "C" void kernel_launch(void* const* d_in, const int* in_sizes, int n_in,
                              void* d_out, int out_size, void* d_ws, size_t ws_size,
                              hipStream_t stream) {
    const float* prob = (const float*)d_in[0];   // [8,3,64,64] f32
    const int*   gt   = (const int*)d_in[1];     // [8,3,100,2] i32
    float* out = (float*)d_out;                  // [8] f32

    hipMemsetAsync(out, 0, (size_t)out_size * sizeof(float), stream);

    const int nblocks = 8 * 2 * NT;   // 1600 blocks, one per (b,c,t)
    betti_block<<<nblocks, 256, 0, stream>>>(prob, gt, out);
}

// Round 12
// 18.807 us; speedup vs baseline: 3.0131x; 1.7593x over previous
//
#include <hip/hip_runtime.h>

typedef unsigned long long ull;
#define NT 100

// Lock-free min-root union-find in LDS. Parent strictly decreases along
// chains -> termination, no cycles.
__device__ __forceinline__ int find_root(int* P, int x) {
    int p = P[x];
    while (p != x) {
        int gp = P[p];
        P[x] = gp;          // benign racy path-halving (gp is an ancestor, gp < x)
        x = gp;
        p = P[x];
    }
    return x;
}

// Returns 1 iff this call performed the hook (merged two distinct trees).
// Per-BLOCK total of successful hooks == components merged: schedule-
// invariant, so the block-combined value is deterministic.
__device__ __forceinline__ int unite(int* P, int a, int b) {
    a = find_root(P, a);
    b = find_root(P, b);
    while (a != b) {
        if (a < b) { int t = a; a = b; b = t; }   // hook larger under smaller
        int old = atomicCAS(&P[a], a, b);
        if (old == a) return 1;
        a = find_root(P, old);
        b = find_root(P, b);
    }
    return 0;
}

// One 256-thread block per (b, c, t) tile. XCD-aware swizzle: dispatch d goes
// to XCD d%8 (round-robin), so tile = (d&7)*200 + (d>>3) gives XCD x the
// contiguous tile range [x*200, x*200+200) = images (b=x, c=0|1) -> each XCD
// reads 32 KB from HBM once, everything else hits its private L2.
// 1600 % 8 == 0 -> bijective. Wave h owns column quarter [16h,16h+16).
__global__ __launch_bounds__(256)
void betti_partial(const float* __restrict__ prob,   // [8,3,64,64]
                   ull* __restrict__ ws)             // [1600*4]
{
    __shared__ int P[2048];
    __shared__ int bL[3][64];                 // run id at col 16h+15, or -1
    __shared__ int bR[3][64];                 // run id at col 16(h+1), or -1

    const int d    = blockIdx.x;
    const int tile = (d & 7) * 200 + (d >> 3);   // (b*2 + c)*100 + t
    const int t    = tile % NT;
    const int cb   = tile / NT;

    const float thr = (float)t * (1.0f / 99.0f);
    const float* img = prob + (size_t)((cb >> 1) * 3 + (cb & 1)) * 4096;

    const int tid  = threadIdx.x;
    const int h    = tid >> 6;                // wave = column quarter
    const int lane = tid & 63;                // row

    // ---- load row `lane`, cols 16h..16h+15 (4 x float4), build 16-bit mask ----
    const float4* rp = (const float4*)(img + (lane << 6) + (h << 4));
    unsigned int m = 0;
    #pragma unroll
    for (int q = 0; q < 4; ++q) {
        float4 v = rp[q];
        m |= (unsigned)(v.x > thr) << (4 * q + 0);
        m |= (unsigned)(v.y > thr) << (4 * q + 1);
        m |= (unsigned)(v.z > thr) << (4 * q + 2);
        m |= (unsigned)(v.w > thr) << (4 * q + 3);
    }

    // ---- init my 8 UF slots (only my wave touches them pre-barrier) ----
    #pragma unroll
    for (int k = 0; k < 8; ++k) {
        int s = ((h * 8 + k) << 6) | lane;
        P[s] = s;
    }

    const unsigned um = m & 0xFFFFu;
    unsigned up        = (unsigned)__shfl_up((int)um, 1, 64);
    unsigned starts    = um & ~(um << 1) & 0xFFFFu;       // run starts
    unsigned starts_up = (unsigned)__shfl_up((int)starts, 1, 64);
    if (lane == 0) { up = 0u; starts_up = 0u; }

    const int px    = __popc(um);
    int       eh    = __popc(um & (um >> 1));             // horiz edges in quarter
    const int ev    = __popc(um & up);                    // vert edges in quarter
    const int nruns = __popc(starts);

    // ---- boundary descriptors (written pre-barrier, read post-barrier) ----
    if (h < 3)   // run containing col15 is the last-starting run: index nruns-1
        bL[h][lane] = ((um >> 15) & 1u) ? (((h * 8 + (nruns - 1)) << 6) | lane) : -1;
    if (h > 0)   // if col 16h is set, it is a run start: index 0
        bR[h - 1][lane] = (um & 1u) ? (((h * 8) << 6) | lane) : -1;

    // ---- within-quarter vertical-overlap unions (own slots only) ----
    int merges = 0;
    unsigned ov = um & up;
    unsigned ss = ov & ~(ov << 1) & 0xFFFFu;              // segment starts
    while (ss) {
        int j = __ffs(ss) - 1;
        ss &= ss - 1;
        unsigned le = (2u << j) - 1;                      // bits [0..j]
        int kc = __popc(starts    & le) - 1;
        int ku = __popc(starts_up & le) - 1;
        merges += unite(P, ((h * 8 + kc) << 6) | lane, ((h * 8 + ku) << 6) | (lane - 1));
    }

    __syncthreads();   // all inits + bL/bR + (disjoint) within-unions visible

    // ---- boundary unions + crossing horizontal edges (waves 0..2) ----
    if (h < 3) {
        int l = bL[h][lane], r = bR[h][lane];
        if (l >= 0 && r >= 0) { eh++; merges += unite(P, l, r); }
    }

    // ---- packed {px(13)|eh(12)|ev(12)|nruns(12)|merges(12)} wave reduce ----
    // block totals: px<=4096, eh<=4032, ev<=4032, nruns<=2048, merges<2048
    ull pk = (ull)px
           | ((ull)eh     << 13)
           | ((ull)ev     << 25)
           | ((ull)nruns  << 37)
           | ((ull)merges << 49);
    #pragma unroll
    for (int o = 32; o > 0; o >>= 1)
        pk += __shfl_down(pk, o, 64);

    if (lane == 0) ws[(size_t)tile * 4 + h] = pk;         // plain store
}

// 8 blocks: block b combines 200 (c,t) tiles' 4 wave-partials each,
// does the betti math + gt |diff|, plain-stores out[b]. Block b lands on
// XCD b (8 blocks, round-robin) -> reads ws written by XCD b: local L2.
__global__ __launch_bounds__(256)
void betti_final(const ull* __restrict__ ws,
                 const int* __restrict__ gt,              // [8,3,100,2]
                 float* __restrict__ out)                 // [8]
{
    __shared__ int wsum[4];
    const int b = blockIdx.x;
    const int tid = threadIdx.x;

    int contrib = 0;
    if (tid < 200) {                                      // tid = c*100 + t
        const ull* p = ws + (size_t)(b * 200 + tid) * 4;
        ull s = p[0] + p[1] + p[2] + p[3];
        const int px = (int)( s        & 0x1FFF);
        const int eh = (int)((s >> 13) & 0xFFF);
        const int ev = (int)((s >> 25) & 0xFFF);
        const int nr = (int)((s >> 37) & 0xFFF);
        const int mg = (int)((s >> 49) & 0xFFF);
        const int b0 = nr - mg;
        const int b1 = b0 - (px - (eh + ev));

        const int c = tid / 100;
        const int t = tid - c * 100;
        int d;
        if (c == 0) {
            const int* g0 = gt + (((size_t)b * 3 + 0) * NT + t) * 2;
            const int* g2 = gt + (((size_t)b * 3 + 2) * NT + t) * 2;
            d = b0 - g0[0]; contrib += d < 0 ? -d : d;
            d = b1 - g0[1]; contrib += d < 0 ? -d : d;
            d = b0 - g2[0]; contrib += d < 0 ? -d : d;
            d = b1 - g2[1]; contrib += d < 0 ? -d : d;
        } else {
            const int* g1 = gt + (((size_t)b * 3 + 1) * NT + t) * 2;
            d = b0 - g1[0]; contrib += d < 0 ? -d : d;
            d = b1 - g1[1]; contrib += d < 0 ? -d : d;
        }
    }

    #pragma unroll
    for (int o = 32; o > 0; o >>= 1) contrib += __shfl_down(contrib, o, 64);
    if ((tid & 63) == 0) wsum[tid >> 6] = contrib;
    __syncthreads();
    if (tid == 0)
        out[b] = (float)(wsum[0] + wsum[1] + wsum[2] + wsum[3]);
}

extern "C" void kernel_launch(void* const* d_in, const int* in_sizes, int n_in,
                              void* d_out, int out_size, void* d_ws, size_t ws_size,
                              hipStream_t stream) {
    const float* prob = (const float*)d_in[0];   // [8,3,64,64] f32
    const int*   gt   = (const int*)d_in[1];     // [8,3,100,2] i32
    float* out = (float*)d_out;                  // [8] f32
    ull* ws = (ull*)d_ws;                        // 1600*4 u64 scratch

    const int nblocks = 8 * 2 * NT;   // 1600 blocks, one per (b,c,t)
    betti_partial<<<nblocks, 256, 0, stream>>>(prob, ws);
    betti_final<<<8, 256, 0, stream>>>(ws, gt, out);
}